// Round 2
// baseline (882.686 us; speedup 1.0000x reference)
//
#include <hip/hip_runtime.h>
#include <stdint.h>

#define NFULL 1024
#define NHUB  512
#define NTOP  256
#define EFULL 523776
#define EHUB  130816
#define ETOP  32640
#define ETOT  (ETOP + EHUB + EFULL)   // 687232
#define NTOT  (NTOP + NHUB + NFULL)   // 1792
// h/xh row-buffer offsets (floats): top 256*128, hub 512*64, full 1024*64
#define HOFF_H 32768
#define HOFF_F 65536
#define HTOT   131072
#define SLOPE 0.01f

// k_ea_all: 256 edges/block, 8 edges x 8 cols per thread
#define NB_T3 128    // ceil(32640/256)
#define NB_H3 511    // 130816/256 exact
#define NB_F3 2046   // 523776/256 exact

// k_tri_tiled: 64x64 tiles over upper-tri tile grid
#define TT_T 10      // nt=4  -> 4+3+2+1
#define TT_H 36      // nt=8
#define TT_F 136     // nt=16

__device__ __forceinline__ int trioff(int i, int n){ return (i * (2 * n - i - 1)) >> 1; }

// invT[e]=-1, invH[e]=-1 for all full edges
__global__ void k_init(int* __restrict__ invT, int* __restrict__ invH)
{
  int t = blockIdx.x * 256 + threadIdx.x;
  if (t < EFULL){ invT[t] = -1; invH[t] = -1; }
}

// scatter branch-local ids into full-edge-indexed inverse maps
__global__ void k_inv(const int* __restrict__ tmask, const int* __restrict__ hmask,
                      int* __restrict__ invT, int* __restrict__ invH)
{
  int t = blockIdx.x * 256 + threadIdx.x;
  if (t < ETOP) invT[tmask[t]] = t;
  else if (t < ETOP + EHUB) invH[hmask[t - ETOP]] = t - ETOP;
}

// ea = leaky(edge_z[ef] @ W + b) -> compact eat[ebase+e][64]; mean -> w2_all.
// Register-tiled GEMM: thread = 8 edges x 8 cols (64 acc). LDS per b128 read
// feeds 16 FMA (vs 4 before) -> LDS traffic 11.3 GB -> 2.75 GB.
// sA chunk index XOR-swizzled by (row>>3)&7: column reads across the 8
// row-groups of a wave hit 8 distinct bank quads -> conflict-free.
__global__ __launch_bounds__(256, 2)
void k_ea_all(const float* __restrict__ ez,
              const int* __restrict__ tmask, const int* __restrict__ hmask,
              const float* __restrict__ Wt, const float* __restrict__ bt,
              const float* __restrict__ Wh, const float* __restrict__ bh,
              const float* __restrict__ Wf, const float* __restrict__ bf,
              float* __restrict__ eat, float* __restrict__ w2_all)
{
  __shared__ float sW[4096];    // 64 x 64
  __shared__ float sA[16384];   // 256 edges x 64, chunk-swizzled
  int b = blockIdx.x, tid = threadIdx.x;
  int bloc, w2off, E; const int* mask; const float* W; const float* bb;
  if (b < NB_T3)               { bloc = b;                 E = ETOP;  w2off = 0;           mask = tmask;   W = Wt; bb = bt; }
  else if (b < NB_T3 + NB_H3)  { bloc = b - NB_T3;         E = EHUB;  w2off = ETOP;        mask = hmask;   W = Wh; bb = bh; }
  else                         { bloc = b - NB_T3 - NB_H3; E = EFULL; w2off = ETOP + EHUB; mask = nullptr; W = Wf; bb = bf; }
  int e0 = bloc * 256;
  {
    const float4* Wv = (const float4*)W;
    float4* sWv = (float4*)sW;
    #pragma unroll
    for (int q = 0; q < 4; q++) sWv[q * 256 + tid] = Wv[q * 256 + tid];
  }
  // stage 256 edge rows (coalesced 256B segments, gathered via mask)
  #pragma unroll
  for (int it = 0; it < 16; it++){
    int idx = it * 256 + tid;
    int row = idx >> 4, ch = idx & 15;
    int er = e0 + row;
    int ec = er < E ? er : (E - 1);
    int ef = mask ? mask[ec] : ec;
    float4 v = *(const float4*)(ez + (size_t)ef * 64 + ch * 4);
    int sch = ch ^ ((row >> 3) & 7);
    *(float4*)(sA + row * 64 + sch * 4) = v;
  }
  __syncthreads();

  int g = tid >> 3, c8 = tid & 7;   // rows g*8..g*8+7, cols c8*8..c8*8+7
  int rbase = g * 8;
  int swz = (g & 7) << 2;           // (row>>3)&7 == g for this thread's rows
  const float* wbase = sW + c8 * 8;

  float bias[8];
  #pragma unroll
  for (int j = 0; j < 8; j++) bias[j] = bb[c8 * 8 + j];
  float acc[8][8];
  #pragma unroll
  for (int e = 0; e < 8; e++)
    #pragma unroll
    for (int j = 0; j < 8; j++) acc[e][j] = bias[j];

  #pragma unroll
  for (int ch = 0; ch < 16; ch++){
    int sa_off = (ch << 2) ^ swz;
    float4 a[8];
    #pragma unroll
    for (int e = 0; e < 8; e++) a[e] = *(const float4*)(sA + (rbase + e) * 64 + sa_off);
    #pragma unroll
    for (int q = 0; q < 4; q++){
      const float* wr = wbase + (ch * 4 + q) * 64;
      float4 w0 = *(const float4*)(wr);
      float4 w1 = *(const float4*)(wr + 4);
      float wv[8]; wv[0]=w0.x; wv[1]=w0.y; wv[2]=w0.z; wv[3]=w0.w;
      wv[4]=w1.x; wv[5]=w1.y; wv[6]=w1.z; wv[7]=w1.w;
      #pragma unroll
      for (int e = 0; e < 8; e++){
        float av = (q == 0) ? a[e].x : (q == 1) ? a[e].y : (q == 2) ? a[e].z : a[e].w;
        #pragma unroll
        for (int j = 0; j < 8; j++) acc[e][j] += av * wv[j];
      }
    }
  }

  // leaky + per-edge partial sums, reduce across the 8 col-lanes (low 3 bits)
  float psum[8];
  #pragma unroll
  for (int e = 0; e < 8; e++){
    float s = 0.f;
    #pragma unroll
    for (int j = 0; j < 8; j++){
      float v = acc[e][j];
      v = v >= 0.f ? v : SLOPE * v;
      acc[e][j] = v; s += v;
    }
    psum[e] = s;
  }
  #pragma unroll
  for (int o = 1; o < 8; o <<= 1)
    #pragma unroll
    for (int e = 0; e < 8; e++) psum[e] += __shfl_xor(psum[e], o);
  if (c8 == 0){
    #pragma unroll
    for (int e = 0; e < 8; e++){
      int er = e0 + rbase + e;
      if (er < E) w2_all[w2off + er] = psum[e] * (1.0f / 64.0f);
    }
  }
  #pragma unroll
  for (int e = 0; e < 8; e++){
    int er = e0 + rbase + e;
    if (er < E){
      float* orow = eat + (size_t)(w2off + er) * 64 + c8 * 8;
      float4 o0; o0.x = acc[e][0]; o0.y = acc[e][1]; o0.z = acc[e][2]; o0.w = acc[e][3];
      float4 o1; o1.x = acc[e][4]; o1.y = acc[e][5]; o1.z = acc[e][6]; o1.w = acc[e][7];
      *(float4*)(orow) = o0;
      *(float4*)(orow + 4) = o1;
    }
  }
}

// deg[i] = 1 + sum_j!=i w2[e(i,j)] via closed-form edge ids; dinv = rsqrt(deg)
__global__ void k_deg_all(const float* __restrict__ w2_all, float* __restrict__ dinv_all)
{
  int b = blockIdx.x, l = threadIdx.x;
  int n, i, boff; const float* w2;
  if (b < NTOP)             { n = NTOP;  i = b;               boff = 0;           w2 = w2_all; }
  else if (b < NTOP + NHUB) { n = NHUB;  i = b - NTOP;        boff = NTOP;        w2 = w2_all + ETOP; }
  else                      { n = NFULL; i = b - NTOP - NHUB; boff = NTOP + NHUB; w2 = w2_all + ETOP + EHUB; }
  float s = 0.f;
  for (int j = l; j < n; j += 64){
    if (j == i) continue;
    int e = (j < i) ? (trioff(j, n) + i - j - 1) : (trioff(i, n) + j - i - 1);
    s += w2[e];
  }
  #pragma unroll
  for (int o = 32; o > 0; o >>= 1) s += __shfl_down(s, o);
  if (l == 0){
    float deg = s + 1.0f;
    dinv_all[boff + i] = (deg > 0.f) ? rsqrtf(deg) : 0.f;
  }
}

// h = concat(node_hidden[gidx], weather) @ gW  (no bias)
__global__ void k_h_all(const float* __restrict__ nodez,
                        const float* __restrict__ wx, const float* __restrict__ hwx,
                        const float* __restrict__ twx,
                        const int* __restrict__ hidx, const int* __restrict__ tidx,
                        const float* __restrict__ gWt, const float* __restrict__ gWh,
                        const float* __restrict__ gWf,
                        float* __restrict__ h_all)
{
  int t = blockIdx.x * 256 + threadIdx.x;
  if (t >= HTOT) return;
  int i, c, gout, nrow; const float* gW; const float* wxp; const int* gidx; float* hp;
  if (t < HOFF_H)      { gout = 128; i = t / 128;  c = t & 127; gW = gWt; wxp = twx; gidx = tidx; hp = h_all; }
  else if (t < HOFF_F) { int u = t - HOFF_H; gout = 64; i = u / 64; c = u & 63; gW = gWh; wxp = hwx; gidx = hidx; hp = h_all + HOFF_H; }
  else                 { int u = t - HOFF_F; gout = 64; i = u / 64; c = u & 63; gW = gWf; wxp = wx;  gidx = nullptr; hp = h_all + HOFF_F; }
  nrow = gidx ? gidx[i] : i;
  const float* nr = nodez + (size_t)nrow * 128;
  float acc = 0.f;
  for (int k = 0; k < 128; k++) acc += nr[k] * gW[k * gout + c];
  const float* wr = wxp + (size_t)i * 16;
  for (int k = 0; k < 16; k++) acc += wr[k] * gW[(128 + k) * gout + c];
  hp[(size_t)i * gout + c] = acc;
}

// xh[i][c] = leaky( dinv[i] * sum_j coef(i,j)*dinv[j]*h[j][c] + b[c] )
__global__ void k_xh_all(const float* __restrict__ w2_all, const float* __restrict__ dinv_all,
                         const float* __restrict__ h_all,
                         const float* __restrict__ gbt, const float* __restrict__ gbh,
                         const float* __restrict__ gbf,
                         float* __restrict__ xh_all)
{
  __shared__ float part[256];
  int b = blockIdx.x, tid = threadIdx.x;
  int n, i, gout; const float* w2; const float* dinv; const float* hb; const float* gb; float* xb;
  if (b < NTOP){
    n = NTOP; i = b; gout = 128;
    w2 = w2_all; dinv = dinv_all; hb = h_all; gb = gbt; xb = xh_all;
  } else if (b < NTOP + NHUB){
    n = NHUB; i = b - NTOP; gout = 64;
    w2 = w2_all + ETOP; dinv = dinv_all + NTOP; hb = h_all + HOFF_H; gb = gbh; xb = xh_all + HOFF_H;
  } else {
    n = NFULL; i = b - NTOP - NHUB; gout = 64;
    w2 = w2_all + ETOP + EHUB; dinv = dinv_all + NTOP + NHUB; hb = h_all + HOFF_F; gb = gbf; xb = xh_all + HOFF_F;
  }
  int SJ = 256 / gout;
  int c = tid & (gout - 1);
  int js = tid / gout;
  float acc = 0.f;
  for (int j = js; j < n; j += SJ){
    float coef;
    if (j == i) coef = 1.0f;
    else {
      int e = (j < i) ? (trioff(j, n) + i - j - 1) : (trioff(i, n) + j - i - 1);
      coef = w2[e];
    }
    coef *= dinv[j];
    acc += coef * hb[(size_t)j * gout + c];
  }
  part[tid] = acc;
  __syncthreads();
  if (js == 0){
    float s = acc;
    for (int q = 1; q < SJ; q++) s += part[q * gout + c];
    s = dinv[i] * s + gb[c];
    xb[(size_t)i * gout + c] = s >= 0.f ? s : SLOPE * s;
  }
}

// tri = sigmoid(xh @ xh^T) on strict upper triangle, computed as a tiled LDS
// GEMM (adj arrays are canonical triu order -> closed-form edge ids).
__global__ __launch_bounds__(256)
void k_tri_tiled(const float* __restrict__ xh_all, float* __restrict__ tri_all)
{
  __shared__ float sXi[8192];   // up to 64 x 128
  __shared__ float sXj[8192];
  int b = blockIdx.x, tid = threadIdx.x;
  int n, g, nt, tt, csh; const float* xb; float* tb;
  if (b < TT_T)        { n = NTOP;  g = 128; nt = 4;  csh = 5; tt = b;            xb = xh_all;          tb = tri_all; }
  else if (b < TT_T+TT_H){ n = NHUB; g = 64; nt = 8;  csh = 4; tt = b - TT_T;     xb = xh_all + HOFF_H; tb = tri_all + ETOP; }
  else                 { n = NFULL; g = 64;  nt = 16; csh = 4; tt = b - TT_T - TT_H; xb = xh_all + HOFF_F; tb = tri_all + ETOP + EHUB; }
  int bi = 0, t = tt;
  while (t >= nt - bi){ t -= nt - bi; bi++; }
  int bj = bi + t;
  int cpr = g >> 2;
  int nch = 64 * cpr;
  const float* gi = xb + (size_t)(bi * 64) * g;
  const float* gj = xb + (size_t)(bj * 64) * g;
  for (int idx = tid; idx < nch; idx += 256){
    int row = idx >> csh;
    int c = idx & (cpr - 1);
    int sw = (c ^ ((row >> 2) & 7)) << 2;
    float4 v = *(const float4*)(gi + (size_t)row * g + c * 4);
    *(float4*)(sXi + row * g + sw) = v;
    float4 w = *(const float4*)(gj + (size_t)row * g + c * 4);
    *(float4*)(sXj + row * g + sw) = w;
  }
  __syncthreads();
  int ii = tid >> 4, jj = tid & 15;
  float acc[4][4];
  #pragma unroll
  for (int a = 0; a < 4; a++)
    #pragma unroll
    for (int q = 0; q < 4; q++) acc[a][q] = 0.f;
  for (int ck = 0; ck < cpr; ck++){
    int swi = (ck ^ (ii & 7)) << 2;
    int swj = (ck ^ (jj & 7)) << 2;
    float4 xi[4], xj[4];
    #pragma unroll
    for (int a = 0; a < 4; a++) xi[a] = *(const float4*)(sXi + (ii * 4 + a) * g + swi);
    #pragma unroll
    for (int q = 0; q < 4; q++) xj[q] = *(const float4*)(sXj + (jj * 4 + q) * g + swj);
    #pragma unroll
    for (int a = 0; a < 4; a++)
      #pragma unroll
      for (int q = 0; q < 4; q++){
        acc[a][q] += xi[a].x * xj[q].x;
        acc[a][q] += xi[a].y * xj[q].y;
        acc[a][q] += xi[a].z * xj[q].z;
        acc[a][q] += xi[a].w * xj[q].w;
      }
  }
  #pragma unroll
  for (int a = 0; a < 4; a++){
    int I = bi * 64 + ii * 4 + a;
    int base = trioff(I, n) - I - 1;
    #pragma unroll
    for (int q = 0; q < 4; q++){
      int J = bj * 64 + jj * 4 + q;
      if (I < J){
        float s = acc[a][q];
        tb[base + J] = 1.f / (1.f + __expf(-s));
      }
    }
  }
}

// out[e][br*64+h] = eat[ebase+eb][h] * (1 + tri*cW[h] + cb[h]) if present, else 0.
__global__ void k_final(const float* __restrict__ eat, const float* __restrict__ tri_all,
                        const int* __restrict__ invT, const int* __restrict__ invH,
                        const float* __restrict__ cwT, const float* __restrict__ cbT,
                        const float* __restrict__ cwH, const float* __restrict__ cbH,
                        const float* __restrict__ cwF, const float* __restrict__ cbF,
                        float* __restrict__ out)
{
  __shared__ float cw[3][64], cb[3][64];
  int lt = threadIdx.x;
  if (lt < 64)       { cw[0][lt] = cwT[lt]; cb[0][lt] = cbT[lt]; }
  else if (lt < 128) { int l = lt - 64;  cw[1][l] = cwH[l]; cb[1][l] = cbH[l]; }
  else if (lt < 192) { int l = lt - 128; cw[2][l] = cwF[l]; cb[2][l] = cbF[l]; }
  __syncthreads();
  int t = blockIdx.x * 256 + threadIdx.x;
  const int TOT = EFULL * 48;
  if (t >= TOT) return;
  int e = t / 48;
  int c = t - e * 48;
  int br = c >> 4, h0 = (c & 15) * 4;
  int eb, ebase; const float* tri;
  if (br == 0)      { eb = invT[e]; tri = tri_all;               ebase = 0; }
  else if (br == 1) { eb = invH[e]; tri = tri_all + ETOP;        ebase = ETOP; }
  else              { eb = e;       tri = tri_all + ETOP + EHUB; ebase = ETOP + EHUB; }
  float* p = out + (size_t)e * 192 + br * 64 + h0;
  if (eb >= 0){
    float tv = tri[eb];
    const float* q = eat + (size_t)(ebase + eb) * 64 + h0;
    float4 v = *(const float4*)q;
    float4 o;
    o.x = v.x * (1.f + tv * cw[br][h0+0] + cb[br][h0+0]);
    o.y = v.y * (1.f + tv * cw[br][h0+1] + cb[br][h0+1]);
    o.z = v.z * (1.f + tv * cw[br][h0+2] + cb[br][h0+2]);
    o.w = v.w * (1.f + tv * cw[br][h0+3] + cb[br][h0+3]);
    *(float4*)p = o;
  } else {
    float4 z; z.x = 0.f; z.y = 0.f; z.z = 0.f; z.w = 0.f;
    *(float4*)p = z;
  }
}

extern "C" void kernel_launch(void* const* d_in, const int* in_sizes, int n_in,
                              void* d_out, int out_size, void* d_ws, size_t ws_size,
                              hipStream_t stream)
{
  const float* nodez  = (const float*)d_in[0];
  const float* wx     = (const float*)d_in[1];
  const float* hub_wx = (const float*)d_in[2];
  const float* top_wx = (const float*)d_in[3];
  const float* ez     = (const float*)d_in[4];
  const int* hidx  = (const int*)d_in[8];
  const int* tidx  = (const int*)d_in[9];
  const int* hmask = (const int*)d_in[13];
  const int* tmask = (const int*)d_in[14];
  const float* dgW_t = (const float*)d_in[15];
  const float* dgb_t = (const float*)d_in[16];
  const float* gW_t  = (const float*)d_in[17];
  const float* gb_t  = (const float*)d_in[18];
  const float* cW_t  = (const float*)d_in[19];
  const float* cb_t  = (const float*)d_in[20];
  const float* dgW_h = (const float*)d_in[21];
  const float* dgb_h = (const float*)d_in[22];
  const float* gW_h  = (const float*)d_in[23];
  const float* gb_h  = (const float*)d_in[24];
  const float* cW_h  = (const float*)d_in[25];
  const float* cb_h  = (const float*)d_in[26];
  const float* dgW_f = (const float*)d_in[27];
  const float* dgb_f = (const float*)d_in[28];
  const float* gW_f  = (const float*)d_in[29];
  const float* gb_f  = (const float*)d_in[30];
  const float* cW_f  = (const float*)d_in[31];
  const float* cb_f  = (const float*)d_in[32];

  char* w = (char*)d_ws;
  size_t off = 0;
  auto alloc = [&](size_t bytes) -> char* {
    char* p = w + off;
    off += (bytes + 255) & ~(size_t)255;
    return p;
  };
  float* w2_all   = (float*)alloc((size_t)ETOT * 4);
  float* tri_all  = (float*)alloc((size_t)ETOT * 4);
  float* dinv_all = (float*)alloc((size_t)NTOT * 4);
  float* h_all    = (float*)alloc((size_t)HTOT * 4);
  float* xh_all   = (float*)alloc((size_t)HTOT * 4);
  int* invT       = (int*)alloc((size_t)EFULL * 4);
  int* invH       = (int*)alloc((size_t)EFULL * 4);
  float* eat      = (float*)alloc((size_t)ETOT * 64 * 4);   // ~176 MB, ws is ~1.6 GB
  (void)ws_size; (void)in_sizes; (void)n_in; (void)out_size;

  float* outp = (float*)d_out;

  k_init<<<(EFULL + 255) / 256, 256, 0, stream>>>(invT, invH);
  k_inv<<<(ETOP + EHUB + 255) / 256, 256, 0, stream>>>(tmask, hmask, invT, invH);
  k_ea_all<<<NB_T3 + NB_H3 + NB_F3, 256, 0, stream>>>(ez, tmask, hmask,
      dgW_t, dgb_t, dgW_h, dgb_h, dgW_f, dgb_f, eat, w2_all);
  k_h_all<<<(HTOT + 255) / 256, 256, 0, stream>>>(nodez, wx, hub_wx, top_wx,
      hidx, tidx, gW_t, gW_h, gW_f, h_all);
  k_deg_all<<<NTOT, 64, 0, stream>>>(w2_all, dinv_all);
  k_xh_all<<<NTOT, 256, 0, stream>>>(w2_all, dinv_all, h_all, gb_t, gb_h, gb_f, xh_all);
  k_tri_tiled<<<TT_T + TT_H + TT_F, 256, 0, stream>>>(xh_all, tri_all);
  k_final<<<(EFULL * 48 + 255) / 256, 256, 0, stream>>>(
      eat, tri_all, invT, invH, cW_t, cb_t, cW_h, cb_h, cW_f, cb_f, outp);
}

// Round 3
// 882.682 us; speedup vs baseline: 1.0000x; 1.0000x over previous
//
#include <hip/hip_runtime.h>
#include <stdint.h>

#define NFULL 1024
#define NHUB  512
#define NTOP  256
#define EFULL 523776
#define EHUB  130816
#define ETOP  32640
#define ETOT  (ETOP + EHUB + EFULL)   // 687232
#define NTOT  (NTOP + NHUB + NFULL)   // 1792
// h/xh row-buffer offsets (floats): top 256*128, hub 512*64, full 1024*64
#define HOFF_H 32768
#define HOFF_F 65536
#define HTOT   131072
#define H4TOT  32768                  // HTOT/4 (one float4 per thread)
#define SLOPE 0.01f

// k_ea_all: 128 edges/block, 2 threads/edge (r1 config, measured best)
#define NB_T2 255    // 32640/128
#define NB_H2 1022   // 130816/128
#define NB_F2 4092   // 523776/128

// k_tri_tiled: 64x64 tiles over upper-tri tile grid
#define TT_T 10      // nt=4  -> 4+3+2+1
#define TT_H 36      // nt=8
#define TT_F 136     // nt=16

__device__ __forceinline__ int trioff(int i, int n){ return (i * (2 * n - i - 1)) >> 1; }

// invT[e]=-1, invH[e]=-1 for all full edges
__global__ void k_init(int* __restrict__ invT, int* __restrict__ invH)
{
  int t = blockIdx.x * 256 + threadIdx.x;
  if (t < EFULL){ invT[t] = -1; invH[t] = -1; }
}

// scatter branch-local ids into full-edge-indexed inverse maps
__global__ void k_inv(const int* __restrict__ tmask, const int* __restrict__ hmask,
                      int* __restrict__ invT, int* __restrict__ invH)
{
  int t = blockIdx.x * 256 + threadIdx.x;
  if (t < ETOP) invT[tmask[t]] = t;
  else if (t < ETOP + EHUB) invH[hmask[t - ETOP]] = t - ETOP;
}

// ea = leaky(edge_z[ef] @ W + b) -> compact eat[ebase+t][64]; mean -> w2_all.
// 2 threads per edge (c0 = 0/32): 32 acc VGPRs/thread -> 16 waves/CU
// (measured-best config from round 1; occupancy beats LDS-traffic here).
__global__ __launch_bounds__(256, 4)
void k_ea_all(const float* __restrict__ ez,
              const int* __restrict__ tmask, const int* __restrict__ hmask,
              const float* __restrict__ Wt, const float* __restrict__ bt,
              const float* __restrict__ Wh, const float* __restrict__ bh,
              const float* __restrict__ Wf, const float* __restrict__ bf,
              float* __restrict__ eat, float* __restrict__ w2_all)
{
  __shared__ float sW[4096];
  __shared__ float sB[64];
  int b = blockIdx.x, tid = threadIdx.x;
  int bloc, w2off; const int* mask; const float* W; const float* bb;
  if (b < NB_T2)               { bloc = b;                 w2off = 0;           mask = tmask;   W = Wt; bb = bt; }
  else if (b < NB_T2 + NB_H2)  { bloc = b - NB_T2;         w2off = ETOP;        mask = hmask;   W = Wh; bb = bh; }
  else                         { bloc = b - NB_T2 - NB_H2; w2off = ETOP + EHUB; mask = nullptr; W = Wf; bb = bf; }
  {
    const float4* Wv = (const float4*)W;
    float4* sWv = (float4*)sW;
    #pragma unroll
    for (int q = 0; q < 4; q++) sWv[q * 256 + tid] = Wv[q * 256 + tid];
    if (tid < 64) sB[tid] = bb[tid];
  }
  __syncthreads();
  int e_loc = bloc * 128 + (tid >> 1);
  int c0 = (tid & 1) * 32;
  int ef = mask ? mask[e_loc] : e_loc;
  const float4* row4 = (const float4*)(ez + (size_t)ef * 64);

  float acc[32];
  #pragma unroll
  for (int j = 0; j < 32; j++) acc[j] = sB[c0 + j];
  #pragma unroll
  for (int k0 = 0; k0 < 64; k0 += 4){
    float4 a4 = row4[k0 >> 2];
    float av[4]; av[0]=a4.x; av[1]=a4.y; av[2]=a4.z; av[3]=a4.w;
    #pragma unroll
    for (int q = 0; q < 4; q++){
      float a = av[q];
      const float* wr = sW + (k0 + q) * 64 + c0;
      #pragma unroll
      for (int j0 = 0; j0 < 32; j0 += 4){
        float4 w4 = *(const float4*)(wr + j0);
        acc[j0+0] += a * w4.x;
        acc[j0+1] += a * w4.y;
        acc[j0+2] += a * w4.z;
        acc[j0+3] += a * w4.w;
      }
    }
  }
  float s = 0.f;
  #pragma unroll
  for (int j = 0; j < 32; j++){
    float v = acc[j];
    v = v >= 0.f ? v : SLOPE * v;
    acc[j] = v; s += v;
  }
  s += __shfl_xor(s, 1);
  if ((tid & 1) == 0) w2_all[w2off + e_loc] = s * (1.0f / 64.0f);
  float* orow = eat + (size_t)(w2off + e_loc) * 64 + c0;
  #pragma unroll
  for (int j0 = 0; j0 < 32; j0 += 4){
    float4 o; o.x = acc[j0]; o.y = acc[j0+1]; o.z = acc[j0+2]; o.w = acc[j0+3];
    *(float4*)(orow + j0) = o;
  }
}

// deg[i] = 1 + sum_j!=i w2[e(i,j)] via closed-form edge ids; dinv = rsqrt(deg)
__global__ void k_deg_all(const float* __restrict__ w2_all, float* __restrict__ dinv_all)
{
  int b = blockIdx.x, l = threadIdx.x;
  int n, i, boff; const float* w2;
  if (b < NTOP)             { n = NTOP;  i = b;               boff = 0;           w2 = w2_all; }
  else if (b < NTOP + NHUB) { n = NHUB;  i = b - NTOP;        boff = NTOP;        w2 = w2_all + ETOP; }
  else                      { n = NFULL; i = b - NTOP - NHUB; boff = NTOP + NHUB; w2 = w2_all + ETOP + EHUB; }
  float s = 0.f;
  for (int j = l; j < n; j += 64){
    if (j == i) continue;
    int e = (j < i) ? (trioff(j, n) + i - j - 1) : (trioff(i, n) + j - i - 1);
    s += w2[e];
  }
  #pragma unroll
  for (int o = 32; o > 0; o >>= 1) s += __shfl_down(s, o);
  if (l == 0){
    float deg = s + 1.0f;
    dinv_all[boff + i] = (deg > 0.f) ? rsqrtf(deg) : 0.f;
  }
}

// h = concat(node_hidden[gidx], weather) @ gW  (no bias)
// One float4 of output per thread: gW rows read as coalesced float4,
// nodez row as float4 broadcast. 4x fewer threads / load-instrs than scalar.
__global__ void k_h_all(const float* __restrict__ nodez,
                        const float* __restrict__ wx, const float* __restrict__ hwx,
                        const float* __restrict__ twx,
                        const int* __restrict__ hidx, const int* __restrict__ tidx,
                        const float* __restrict__ gWt, const float* __restrict__ gWh,
                        const float* __restrict__ gWf,
                        float* __restrict__ h_all)
{
  int t = blockIdx.x * 256 + threadIdx.x;
  if (t >= H4TOT) return;
  int i, c4, g4; const float* gW; const float* wxp; const int* gidx; float* hp;
  if (t < 8192)       { g4 = 32; i = t >> 5;  c4 = t & 31; gW = gWt; wxp = twx; gidx = tidx; hp = h_all; }
  else if (t < 16384) { int u = t - 8192;  g4 = 16; i = u >> 4; c4 = u & 15; gW = gWh; wxp = hwx; gidx = hidx; hp = h_all + HOFF_H; }
  else                { int u = t - 16384; g4 = 16; i = u >> 4; c4 = u & 15; gW = gWf; wxp = wx;  gidx = nullptr; hp = h_all + HOFF_F; }
  int nrow = gidx ? gidx[i] : i;
  const float4* nr4 = (const float4*)(nodez + (size_t)nrow * 128);
  const float4* gwc = (const float4*)gW + c4;   // element (k,c4*4) as float4: gwc[k*g4]
  float4 acc; acc.x = acc.y = acc.z = acc.w = 0.f;
  #pragma unroll
  for (int k4 = 0; k4 < 32; k4++){
    float4 a = nr4[k4];
    float4 w0 = gwc[(k4 * 4 + 0) * g4];
    float4 w1 = gwc[(k4 * 4 + 1) * g4];
    float4 w2 = gwc[(k4 * 4 + 2) * g4];
    float4 w3 = gwc[(k4 * 4 + 3) * g4];
    acc.x += a.x * w0.x + a.y * w1.x + a.z * w2.x + a.w * w3.x;
    acc.y += a.x * w0.y + a.y * w1.y + a.z * w2.y + a.w * w3.y;
    acc.z += a.x * w0.z + a.y * w1.z + a.z * w2.z + a.w * w3.z;
    acc.w += a.x * w0.w + a.y * w1.w + a.z * w2.w + a.w * w3.w;
  }
  const float4* wr4 = (const float4*)(wxp + (size_t)i * 16);
  #pragma unroll
  for (int k4 = 0; k4 < 4; k4++){
    float4 a = wr4[k4];
    float4 w0 = gwc[(128 + k4 * 4 + 0) * g4];
    float4 w1 = gwc[(128 + k4 * 4 + 1) * g4];
    float4 w2 = gwc[(128 + k4 * 4 + 2) * g4];
    float4 w3 = gwc[(128 + k4 * 4 + 3) * g4];
    acc.x += a.x * w0.x + a.y * w1.x + a.z * w2.x + a.w * w3.x;
    acc.y += a.x * w0.y + a.y * w1.y + a.z * w2.y + a.w * w3.y;
    acc.z += a.x * w0.z + a.y * w1.z + a.z * w2.z + a.w * w3.z;
    acc.w += a.x * w0.w + a.y * w1.w + a.z * w2.w + a.w * w3.w;
  }
  ((float4*)hp)[(size_t)i * g4 + c4] = acc;
}

// xh[i][c] = leaky( dinv[i] * sum_j coef(i,j)*dinv[j]*h[j][c] + b[c] )
__global__ void k_xh_all(const float* __restrict__ w2_all, const float* __restrict__ dinv_all,
                         const float* __restrict__ h_all,
                         const float* __restrict__ gbt, const float* __restrict__ gbh,
                         const float* __restrict__ gbf,
                         float* __restrict__ xh_all)
{
  __shared__ float part[256];
  int b = blockIdx.x, tid = threadIdx.x;
  int n, i, gout; const float* w2; const float* dinv; const float* hb; const float* gb; float* xb;
  if (b < NTOP){
    n = NTOP; i = b; gout = 128;
    w2 = w2_all; dinv = dinv_all; hb = h_all; gb = gbt; xb = xh_all;
  } else if (b < NTOP + NHUB){
    n = NHUB; i = b - NTOP; gout = 64;
    w2 = w2_all + ETOP; dinv = dinv_all + NTOP; hb = h_all + HOFF_H; gb = gbh; xb = xh_all + HOFF_H;
  } else {
    n = NFULL; i = b - NTOP - NHUB; gout = 64;
    w2 = w2_all + ETOP + EHUB; dinv = dinv_all + NTOP + NHUB; hb = h_all + HOFF_F; gb = gbf; xb = xh_all + HOFF_F;
  }
  int SJ = 256 / gout;
  int c = tid & (gout - 1);
  int js = tid / gout;
  float acc = 0.f;
  for (int j = js; j < n; j += SJ){
    float coef;
    if (j == i) coef = 1.0f;
    else {
      int e = (j < i) ? (trioff(j, n) + i - j - 1) : (trioff(i, n) + j - i - 1);
      coef = w2[e];
    }
    coef *= dinv[j];
    acc += coef * hb[(size_t)j * gout + c];
  }
  part[tid] = acc;
  __syncthreads();
  if (js == 0){
    float s = acc;
    for (int q = 1; q < SJ; q++) s += part[q * gout + c];
    s = dinv[i] * s + gb[c];
    xb[(size_t)i * gout + c] = s >= 0.f ? s : SLOPE * s;
  }
}

// tri = sigmoid(xh @ xh^T) on strict upper triangle, computed as a tiled LDS
// GEMM (adj arrays are canonical triu order -> closed-form edge ids).
__global__ __launch_bounds__(256)
void k_tri_tiled(const float* __restrict__ xh_all, float* __restrict__ tri_all)
{
  __shared__ float sXi[8192];   // up to 64 x 128
  __shared__ float sXj[8192];
  int b = blockIdx.x, tid = threadIdx.x;
  int n, g, nt, tt, csh; const float* xb; float* tb;
  if (b < TT_T)        { n = NTOP;  g = 128; nt = 4;  csh = 5; tt = b;            xb = xh_all;          tb = tri_all; }
  else if (b < TT_T+TT_H){ n = NHUB; g = 64; nt = 8;  csh = 4; tt = b - TT_T;     xb = xh_all + HOFF_H; tb = tri_all + ETOP; }
  else                 { n = NFULL; g = 64;  nt = 16; csh = 4; tt = b - TT_T - TT_H; xb = xh_all + HOFF_F; tb = tri_all + ETOP + EHUB; }
  int bi = 0, t = tt;
  while (t >= nt - bi){ t -= nt - bi; bi++; }
  int bj = bi + t;
  int cpr = g >> 2;
  int nch = 64 * cpr;
  const float* gi = xb + (size_t)(bi * 64) * g;
  const float* gj = xb + (size_t)(bj * 64) * g;
  for (int idx = tid; idx < nch; idx += 256){
    int row = idx >> csh;
    int c = idx & (cpr - 1);
    int sw = (c ^ ((row >> 2) & 7)) << 2;
    float4 v = *(const float4*)(gi + (size_t)row * g + c * 4);
    *(float4*)(sXi + row * g + sw) = v;
    float4 w = *(const float4*)(gj + (size_t)row * g + c * 4);
    *(float4*)(sXj + row * g + sw) = w;
  }
  __syncthreads();
  int ii = tid >> 4, jj = tid & 15;
  float acc[4][4];
  #pragma unroll
  for (int a = 0; a < 4; a++)
    #pragma unroll
    for (int q = 0; q < 4; q++) acc[a][q] = 0.f;
  for (int ck = 0; ck < cpr; ck++){
    int swi = (ck ^ (ii & 7)) << 2;
    int swj = (ck ^ (jj & 7)) << 2;
    float4 xi[4], xj[4];
    #pragma unroll
    for (int a = 0; a < 4; a++) xi[a] = *(const float4*)(sXi + (ii * 4 + a) * g + swi);
    #pragma unroll
    for (int q = 0; q < 4; q++) xj[q] = *(const float4*)(sXj + (jj * 4 + q) * g + swj);
    #pragma unroll
    for (int a = 0; a < 4; a++)
      #pragma unroll
      for (int q = 0; q < 4; q++){
        acc[a][q] += xi[a].x * xj[q].x;
        acc[a][q] += xi[a].y * xj[q].y;
        acc[a][q] += xi[a].z * xj[q].z;
        acc[a][q] += xi[a].w * xj[q].w;
      }
  }
  #pragma unroll
  for (int a = 0; a < 4; a++){
    int I = bi * 64 + ii * 4 + a;
    int base = trioff(I, n) - I - 1;
    #pragma unroll
    for (int q = 0; q < 4; q++){
      int J = bj * 64 + jj * 4 + q;
      if (I < J){
        float s = acc[a][q];
        tb[base + J] = 1.f / (1.f + __expf(-s));
      }
    }
  }
}

// out[e][br*64+h] = eat[ebase+eb][h] * (1 + tri*cW[h] + cb[h]) if present, else 0.
__global__ void k_final(const float* __restrict__ eat, const float* __restrict__ tri_all,
                        const int* __restrict__ invT, const int* __restrict__ invH,
                        const float* __restrict__ cwT, const float* __restrict__ cbT,
                        const float* __restrict__ cwH, const float* __restrict__ cbH,
                        const float* __restrict__ cwF, const float* __restrict__ cbF,
                        float* __restrict__ out)
{
  __shared__ float cw[3][64], cb[3][64];
  int lt = threadIdx.x;
  if (lt < 64)       { cw[0][lt] = cwT[lt]; cb[0][lt] = cbT[lt]; }
  else if (lt < 128) { int l = lt - 64;  cw[1][l] = cwH[l]; cb[1][l] = cbH[l]; }
  else if (lt < 192) { int l = lt - 128; cw[2][l] = cwF[l]; cb[2][l] = cbF[l]; }
  __syncthreads();
  int t = blockIdx.x * 256 + threadIdx.x;
  const int TOT = EFULL * 48;
  if (t >= TOT) return;
  int e = t / 48;
  int c = t - e * 48;
  int br = c >> 4, h0 = (c & 15) * 4;
  int eb, ebase; const float* tri;
  if (br == 0)      { eb = invT[e]; tri = tri_all;               ebase = 0; }
  else if (br == 1) { eb = invH[e]; tri = tri_all + ETOP;        ebase = ETOP; }
  else              { eb = e;       tri = tri_all + ETOP + EHUB; ebase = ETOP + EHUB; }
  float* p = out + (size_t)e * 192 + br * 64 + h0;
  if (eb >= 0){
    float tv = tri[eb];
    const float* q = eat + (size_t)(ebase + eb) * 64 + h0;
    float4 v = *(const float4*)q;
    float4 o;
    o.x = v.x * (1.f + tv * cw[br][h0+0] + cb[br][h0+0]);
    o.y = v.y * (1.f + tv * cw[br][h0+1] + cb[br][h0+1]);
    o.z = v.z * (1.f + tv * cw[br][h0+2] + cb[br][h0+2]);
    o.w = v.w * (1.f + tv * cw[br][h0+3] + cb[br][h0+3]);
    *(float4*)p = o;
  } else {
    float4 z; z.x = 0.f; z.y = 0.f; z.z = 0.f; z.w = 0.f;
    *(float4*)p = z;
  }
}

extern "C" void kernel_launch(void* const* d_in, const int* in_sizes, int n_in,
                              void* d_out, int out_size, void* d_ws, size_t ws_size,
                              hipStream_t stream)
{
  const float* nodez  = (const float*)d_in[0];
  const float* wx     = (const float*)d_in[1];
  const float* hub_wx = (const float*)d_in[2];
  const float* top_wx = (const float*)d_in[3];
  const float* ez     = (const float*)d_in[4];
  const int* hidx  = (const int*)d_in[8];
  const int* tidx  = (const int*)d_in[9];
  const int* hmask = (const int*)d_in[13];
  const int* tmask = (const int*)d_in[14];
  const float* dgW_t = (const float*)d_in[15];
  const float* dgb_t = (const float*)d_in[16];
  const float* gW_t  = (const float*)d_in[17];
  const float* gb_t  = (const float*)d_in[18];
  const float* cW_t  = (const float*)d_in[19];
  const float* cb_t  = (const float*)d_in[20];
  const float* dgW_h = (const float*)d_in[21];
  const float* dgb_h = (const float*)d_in[22];
  const float* gW_h  = (const float*)d_in[23];
  const float* gb_h  = (const float*)d_in[24];
  const float* cW_h  = (const float*)d_in[25];
  const float* cb_h  = (const float*)d_in[26];
  const float* dgW_f = (const float*)d_in[27];
  const float* dgb_f = (const float*)d_in[28];
  const float* gW_f  = (const float*)d_in[29];
  const float* gb_f  = (const float*)d_in[30];
  const float* cW_f  = (const float*)d_in[31];
  const float* cb_f  = (const float*)d_in[32];

  char* w = (char*)d_ws;
  size_t off = 0;
  auto alloc = [&](size_t bytes) -> char* {
    char* p = w + off;
    off += (bytes + 255) & ~(size_t)255;
    return p;
  };
  float* w2_all   = (float*)alloc((size_t)ETOT * 4);
  float* tri_all  = (float*)alloc((size_t)ETOT * 4);
  float* dinv_all = (float*)alloc((size_t)NTOT * 4);
  float* h_all    = (float*)alloc((size_t)HTOT * 4);
  float* xh_all   = (float*)alloc((size_t)HTOT * 4);
  int* invT       = (int*)alloc((size_t)EFULL * 4);
  int* invH       = (int*)alloc((size_t)EFULL * 4);
  float* eat      = (float*)alloc((size_t)ETOT * 64 * 4);   // ~176 MB, ws is ~1.6 GB
  (void)ws_size; (void)in_sizes; (void)n_in; (void)out_size;

  float* outp = (float*)d_out;

  k_init<<<(EFULL + 255) / 256, 256, 0, stream>>>(invT, invH);
  k_inv<<<(ETOP + EHUB + 255) / 256, 256, 0, stream>>>(tmask, hmask, invT, invH);
  k_ea_all<<<NB_T2 + NB_H2 + NB_F2, 256, 0, stream>>>(ez, tmask, hmask,
      dgW_t, dgb_t, dgW_h, dgb_h, dgW_f, dgb_f, eat, w2_all);
  k_h_all<<<(H4TOT + 255) / 256, 256, 0, stream>>>(nodez, wx, hub_wx, top_wx,
      hidx, tidx, gW_t, gW_h, gW_f, h_all);
  k_deg_all<<<NTOT, 64, 0, stream>>>(w2_all, dinv_all);
  k_xh_all<<<NTOT, 256, 0, stream>>>(w2_all, dinv_all, h_all, gb_t, gb_h, gb_f, xh_all);
  k_tri_tiled<<<TT_T + TT_H + TT_F, 256, 0, stream>>>(xh_all, tri_all);
  k_final<<<(EFULL * 48 + 255) / 256, 256, 0, stream>>>(
      eat, tri_all, invT, invH, cW_t, cb_t, cW_h, cb_h, cW_f, cb_f, outp);
}

// Round 4
// 733.947 us; speedup vs baseline: 1.2027x; 1.2027x over previous
//
#include <hip/hip_runtime.h>
#include <stdint.h>

#define NFULL 1024
#define NHUB  512
#define NTOP  256
#define EFULL 523776
#define EHUB  130816
#define ETOP  32640
#define ETOT  (ETOP + EHUB + EFULL)   // 687232
#define NTOT  (NTOP + NHUB + NFULL)   // 1792
// h/xh row-buffer offsets (floats): top 256*128, hub 512*64, full 1024*64
#define HOFF_H 32768
#define HOFF_F 65536
#define HTOT   131072
#define SLOPE 0.01f

// k_ea_all: 128 edges/block, 2 threads/edge (r1 config, measured best)
#define NB_T2 255    // 32640/128
#define NB_H2 1022   // 130816/128
#define NB_F2 4092   // 523776/128

// k_tri_tiled: 64x64 tiles over upper-tri tile grid
#define TT_T 10      // nt=4  -> 4+3+2+1
#define TT_H 36      // nt=8
#define TT_F 136     // nt=16

// k_zero / k_out segment sizes (all exact multiples of 256 threads)
#define NBZ  65472   // EFULL*32/256   : zero out[:,0:128)
#define NBT4 2040    // ETOP*16/256    : top values -> out[tmask][0:64)
#define NBH4 8176    // EHUB*16/256    : hub values -> out[hmask][64:128)
#define NBF4 32736   // EFULL*16/256   : full values -> out[:,128:192)

__device__ __forceinline__ int trioff(int i, int n){ return (i * (2 * n - i - 1)) >> 1; }

// pre-zero out[:, 0:128) -- pure streaming fill, replaces invT/invH machinery.
// Runs first; top/hub value-writers later overwrite their (sparse) slots.
__global__ __launch_bounds__(256)
void k_zero(float* __restrict__ out)
{
  int t = blockIdx.x * 256 + threadIdx.x;
  int row = t >> 5, c4 = t & 31;
  float4 z; z.x = 0.f; z.y = 0.f; z.z = 0.f; z.w = 0.f;
  *(float4*)(out + (size_t)row * 192 + c4 * 4) = z;
}

// ea = leaky(edge_z[ef] @ W + b) -> compact eat[ebase+t][64]; mean -> w2_all.
// 2 threads per edge (c0 = 0/32): 32 acc VGPRs/thread, 16 waves/CU
// (measured-best config from round 1).
__global__ __launch_bounds__(256, 4)
void k_ea_all(const float* __restrict__ ez,
              const int* __restrict__ tmask, const int* __restrict__ hmask,
              const float* __restrict__ Wt, const float* __restrict__ bt,
              const float* __restrict__ Wh, const float* __restrict__ bh,
              const float* __restrict__ Wf, const float* __restrict__ bf,
              float* __restrict__ eat, float* __restrict__ w2_all)
{
  __shared__ float sW[4096];
  __shared__ float sB[64];
  int b = blockIdx.x, tid = threadIdx.x;
  int bloc, w2off; const int* mask; const float* W; const float* bb;
  if (b < NB_T2)               { bloc = b;                 w2off = 0;           mask = tmask;   W = Wt; bb = bt; }
  else if (b < NB_T2 + NB_H2)  { bloc = b - NB_T2;         w2off = ETOP;        mask = hmask;   W = Wh; bb = bh; }
  else                         { bloc = b - NB_T2 - NB_H2; w2off = ETOP + EHUB; mask = nullptr; W = Wf; bb = bf; }
  {
    const float4* Wv = (const float4*)W;
    float4* sWv = (float4*)sW;
    #pragma unroll
    for (int q = 0; q < 4; q++) sWv[q * 256 + tid] = Wv[q * 256 + tid];
    if (tid < 64) sB[tid] = bb[tid];
  }
  __syncthreads();
  int e_loc = bloc * 128 + (tid >> 1);
  int c0 = (tid & 1) * 32;
  int ef = mask ? mask[e_loc] : e_loc;
  const float4* row4 = (const float4*)(ez + (size_t)ef * 64);

  float acc[32];
  #pragma unroll
  for (int j = 0; j < 32; j++) acc[j] = sB[c0 + j];
  #pragma unroll
  for (int k0 = 0; k0 < 64; k0 += 4){
    float4 a4 = row4[k0 >> 2];
    float av[4]; av[0]=a4.x; av[1]=a4.y; av[2]=a4.z; av[3]=a4.w;
    #pragma unroll
    for (int q = 0; q < 4; q++){
      float a = av[q];
      const float* wr = sW + (k0 + q) * 64 + c0;
      #pragma unroll
      for (int j0 = 0; j0 < 32; j0 += 4){
        float4 w4 = *(const float4*)(wr + j0);
        acc[j0+0] += a * w4.x;
        acc[j0+1] += a * w4.y;
        acc[j0+2] += a * w4.z;
        acc[j0+3] += a * w4.w;
      }
    }
  }
  float s = 0.f;
  #pragma unroll
  for (int j = 0; j < 32; j++){
    float v = acc[j];
    v = v >= 0.f ? v : SLOPE * v;
    acc[j] = v; s += v;
  }
  s += __shfl_xor(s, 1);
  if ((tid & 1) == 0) w2_all[w2off + e_loc] = s * (1.0f / 64.0f);
  float* orow = eat + (size_t)(w2off + e_loc) * 64 + c0;
  #pragma unroll
  for (int j0 = 0; j0 < 32; j0 += 4){
    float4 o; o.x = acc[j0]; o.y = acc[j0+1]; o.z = acc[j0+2]; o.w = acc[j0+3];
    *(float4*)(orow + j0) = o;
  }
}

// deg[i] = 1 + sum_j!=i w2[e(i,j)]; dinv = rsqrt(deg). 256 threads/block
// (4 waves) for 4x latency hiding on the scattered w2 gather.
__global__ void k_deg_all(const float* __restrict__ w2_all, float* __restrict__ dinv_all)
{
  __shared__ float red[4];
  int b = blockIdx.x, l = threadIdx.x;
  int n, i, boff; const float* w2;
  if (b < NTOP)             { n = NTOP;  i = b;               boff = 0;           w2 = w2_all; }
  else if (b < NTOP + NHUB) { n = NHUB;  i = b - NTOP;        boff = NTOP;        w2 = w2_all + ETOP; }
  else                      { n = NFULL; i = b - NTOP - NHUB; boff = NTOP + NHUB; w2 = w2_all + ETOP + EHUB; }
  float s = 0.f;
  for (int j = l; j < n; j += 256){
    if (j == i) continue;
    int e = (j < i) ? (trioff(j, n) + i - j - 1) : (trioff(i, n) + j - i - 1);
    s += w2[e];
  }
  #pragma unroll
  for (int o = 32; o > 0; o >>= 1) s += __shfl_down(s, o);
  if ((l & 63) == 0) red[l >> 6] = s;
  __syncthreads();
  if (l == 0){
    float deg = red[0] + red[1] + red[2] + red[3] + 1.0f;
    dinv_all[boff + i] = (deg > 0.f) ? rsqrtf(deg) : 0.f;
  }
}

// h = concat(node_hidden[gidx], weather) @ gW  (no bias) -- r1-proven scalar form
__global__ void k_h_all(const float* __restrict__ nodez,
                        const float* __restrict__ wx, const float* __restrict__ hwx,
                        const float* __restrict__ twx,
                        const int* __restrict__ hidx, const int* __restrict__ tidx,
                        const float* __restrict__ gWt, const float* __restrict__ gWh,
                        const float* __restrict__ gWf,
                        float* __restrict__ h_all)
{
  int t = blockIdx.x * 256 + threadIdx.x;
  if (t >= HTOT) return;
  int i, c, gout, nrow; const float* gW; const float* wxp; const int* gidx; float* hp;
  if (t < HOFF_H)      { gout = 128; i = t / 128;  c = t & 127; gW = gWt; wxp = twx; gidx = tidx; hp = h_all; }
  else if (t < HOFF_F) { int u = t - HOFF_H; gout = 64; i = u / 64; c = u & 63; gW = gWh; wxp = hwx; gidx = hidx; hp = h_all + HOFF_H; }
  else                 { int u = t - HOFF_F; gout = 64; i = u / 64; c = u & 63; gW = gWf; wxp = wx;  gidx = nullptr; hp = h_all + HOFF_F; }
  nrow = gidx ? gidx[i] : i;
  const float* nr = nodez + (size_t)nrow * 128;
  float acc = 0.f;
  for (int k = 0; k < 128; k++) acc += nr[k] * gW[k * gout + c];
  const float* wr = wxp + (size_t)i * 16;
  for (int k = 0; k < 16; k++) acc += wr[k] * gW[(128 + k) * gout + c];
  hp[(size_t)i * gout + c] = acc;
}

// xh[i][c] = leaky( dinv[i] * sum_j coef(i,j)*dinv[j]*h[j][c] + b[c] )
// Coefs (scattered w2 gathers) staged to LDS once per block; hot loop is a
// pure broadcast-coef x streaming-h FMA chain. Summation order unchanged.
__global__ void k_xh_all(const float* __restrict__ w2_all, const float* __restrict__ dinv_all,
                         const float* __restrict__ h_all,
                         const float* __restrict__ gbt, const float* __restrict__ gbh,
                         const float* __restrict__ gbf,
                         float* __restrict__ xh_all)
{
  __shared__ float coef[1024];
  __shared__ float part[256];
  int b = blockIdx.x, tid = threadIdx.x;
  int n, i, gout; const float* w2; const float* dinv; const float* hb; const float* gb; float* xb;
  if (b < NTOP){
    n = NTOP; i = b; gout = 128;
    w2 = w2_all; dinv = dinv_all; hb = h_all; gb = gbt; xb = xh_all;
  } else if (b < NTOP + NHUB){
    n = NHUB; i = b - NTOP; gout = 64;
    w2 = w2_all + ETOP; dinv = dinv_all + NTOP; hb = h_all + HOFF_H; gb = gbh; xb = xh_all + HOFF_H;
  } else {
    n = NFULL; i = b - NTOP - NHUB; gout = 64;
    w2 = w2_all + ETOP + EHUB; dinv = dinv_all + NTOP + NHUB; hb = h_all + HOFF_F; gb = gbf; xb = xh_all + HOFF_F;
  }
  for (int j = tid; j < n; j += 256){
    float w;
    if (j == i) w = 1.0f;
    else {
      int e = (j < i) ? (trioff(j, n) + i - j - 1) : (trioff(i, n) + j - i - 1);
      w = w2[e];
    }
    coef[j] = w * dinv[j];
  }
  __syncthreads();
  int SJ = 256 / gout;
  int c = tid & (gout - 1);
  int js = tid / gout;
  float acc = 0.f;
  #pragma unroll 4
  for (int j = js; j < n; j += SJ){
    acc += coef[j] * hb[(size_t)j * gout + c];
  }
  part[tid] = acc;
  __syncthreads();
  if (js == 0){
    float s = acc;
    for (int q = 1; q < SJ; q++) s += part[q * gout + c];
    s = dinv[i] * s + gb[c];
    xb[(size_t)i * gout + c] = s >= 0.f ? s : SLOPE * s;
  }
}

// tri = sigmoid(xh @ xh^T) on strict upper triangle, tiled LDS GEMM.
__global__ __launch_bounds__(256)
void k_tri_tiled(const float* __restrict__ xh_all, float* __restrict__ tri_all)
{
  __shared__ float sXi[8192];   // up to 64 x 128
  __shared__ float sXj[8192];
  int b = blockIdx.x, tid = threadIdx.x;
  int n, g, nt, tt, csh; const float* xb; float* tb;
  if (b < TT_T)        { n = NTOP;  g = 128; nt = 4;  csh = 5; tt = b;            xb = xh_all;          tb = tri_all; }
  else if (b < TT_T+TT_H){ n = NHUB; g = 64; nt = 8;  csh = 4; tt = b - TT_T;     xb = xh_all + HOFF_H; tb = tri_all + ETOP; }
  else                 { n = NFULL; g = 64;  nt = 16; csh = 4; tt = b - TT_T - TT_H; xb = xh_all + HOFF_F; tb = tri_all + ETOP + EHUB; }
  int bi = 0, t = tt;
  while (t >= nt - bi){ t -= nt - bi; bi++; }
  int bj = bi + t;
  int cpr = g >> 2;
  int nch = 64 * cpr;
  const float* gi = xb + (size_t)(bi * 64) * g;
  const float* gj = xb + (size_t)(bj * 64) * g;
  for (int idx = tid; idx < nch; idx += 256){
    int row = idx >> csh;
    int c = idx & (cpr - 1);
    int sw = (c ^ ((row >> 2) & 7)) << 2;
    float4 v = *(const float4*)(gi + (size_t)row * g + c * 4);
    *(float4*)(sXi + row * g + sw) = v;
    float4 w = *(const float4*)(gj + (size_t)row * g + c * 4);
    *(float4*)(sXj + row * g + sw) = w;
  }
  __syncthreads();
  int ii = tid >> 4, jj = tid & 15;
  float acc[4][4];
  #pragma unroll
  for (int a = 0; a < 4; a++)
    #pragma unroll
    for (int q = 0; q < 4; q++) acc[a][q] = 0.f;
  for (int ck = 0; ck < cpr; ck++){
    int swi = (ck ^ (ii & 7)) << 2;
    int swj = (ck ^ (jj & 7)) << 2;
    float4 xi[4], xj[4];
    #pragma unroll
    for (int a = 0; a < 4; a++) xi[a] = *(const float4*)(sXi + (ii * 4 + a) * g + swi);
    #pragma unroll
    for (int q = 0; q < 4; q++) xj[q] = *(const float4*)(sXj + (jj * 4 + q) * g + swj);
    #pragma unroll
    for (int a = 0; a < 4; a++)
      #pragma unroll
      for (int q = 0; q < 4; q++){
        acc[a][q] += xi[a].x * xj[q].x;
        acc[a][q] += xi[a].y * xj[q].y;
        acc[a][q] += xi[a].z * xj[q].z;
        acc[a][q] += xi[a].w * xj[q].w;
      }
  }
  #pragma unroll
  for (int a = 0; a < 4; a++){
    int I = bi * 64 + ii * 4 + a;
    int base = trioff(I, n) - I - 1;
    #pragma unroll
    for (int q = 0; q < 4; q++){
      int J = bj * 64 + jj * 4 + q;
      if (I < J){
        float s = acc[a][q];
        tb[base + J] = 1.f / (1.f + __expf(-s));
      }
    }
  }
}

// Value writer, keyed by BRANCH edge: all eat/tri reads fully contiguous,
// branchless per-thread body. Top/hub overwrite slots pre-zeroed by k_zero.
__global__ __launch_bounds__(256)
void k_out(const float* __restrict__ eat, const float* __restrict__ tri_all,
           const int* __restrict__ tmask, const int* __restrict__ hmask,
           const float* __restrict__ cwT, const float* __restrict__ cbT,
           const float* __restrict__ cwH, const float* __restrict__ cbH,
           const float* __restrict__ cwF, const float* __restrict__ cbF,
           float* __restrict__ out)
{
  __shared__ float scw[64], scb[64];
  int b = blockIdx.x, tid = threadIdx.x;
  int boff, col, u; const int* mask; const float* cwp; const float* cbp;
  if (b < NBT4)             { u = b * 256 + tid;                 boff = 0;           col = 0;   mask = tmask;   cwp = cwT; cbp = cbT; }
  else if (b < NBT4 + NBH4) { u = (b - NBT4) * 256 + tid;        boff = ETOP;        col = 64;  mask = hmask;   cwp = cwH; cbp = cbH; }
  else                      { u = (b - NBT4 - NBH4) * 256 + tid; boff = ETOP + EHUB; col = 128; mask = nullptr; cwp = cwF; cbp = cbF; }
  if (tid < 64){ scw[tid] = cwp[tid]; scb[tid] = cbp[tid]; }
  __syncthreads();
  int eb = u >> 4, c4 = u & 15;
  int erow = mask ? mask[eb] : eb;
  float tv = tri_all[boff + eb];
  const float* q = eat + (size_t)(boff + eb) * 64 + c4 * 4;
  float4 v = *(const float4*)q;
  int h0 = c4 * 4;
  float4 o;
  o.x = v.x * (1.f + tv * scw[h0+0] + scb[h0+0]);
  o.y = v.y * (1.f + tv * scw[h0+1] + scb[h0+1]);
  o.z = v.z * (1.f + tv * scw[h0+2] + scb[h0+2]);
  o.w = v.w * (1.f + tv * scw[h0+3] + scb[h0+3]);
  *(float4*)(out + (size_t)erow * 192 + col + h0) = o;
}

extern "C" void kernel_launch(void* const* d_in, const int* in_sizes, int n_in,
                              void* d_out, int out_size, void* d_ws, size_t ws_size,
                              hipStream_t stream)
{
  const float* nodez  = (const float*)d_in[0];
  const float* wx     = (const float*)d_in[1];
  const float* hub_wx = (const float*)d_in[2];
  const float* top_wx = (const float*)d_in[3];
  const float* ez     = (const float*)d_in[4];
  const int* hidx  = (const int*)d_in[8];
  const int* tidx  = (const int*)d_in[9];
  const int* hmask = (const int*)d_in[13];
  const int* tmask = (const int*)d_in[14];
  const float* dgW_t = (const float*)d_in[15];
  const float* dgb_t = (const float*)d_in[16];
  const float* gW_t  = (const float*)d_in[17];
  const float* gb_t  = (const float*)d_in[18];
  const float* cW_t  = (const float*)d_in[19];
  const float* cb_t  = (const float*)d_in[20];
  const float* dgW_h = (const float*)d_in[21];
  const float* dgb_h = (const float*)d_in[22];
  const float* gW_h  = (const float*)d_in[23];
  const float* gb_h  = (const float*)d_in[24];
  const float* cW_h  = (const float*)d_in[25];
  const float* cb_h  = (const float*)d_in[26];
  const float* dgW_f = (const float*)d_in[27];
  const float* dgb_f = (const float*)d_in[28];
  const float* gW_f  = (const float*)d_in[29];
  const float* gb_f  = (const float*)d_in[30];
  const float* cW_f  = (const float*)d_in[31];
  const float* cb_f  = (const float*)d_in[32];

  char* w = (char*)d_ws;
  size_t off = 0;
  auto alloc = [&](size_t bytes) -> char* {
    char* p = w + off;
    off += (bytes + 255) & ~(size_t)255;
    return p;
  };
  float* w2_all   = (float*)alloc((size_t)ETOT * 4);
  float* tri_all  = (float*)alloc((size_t)ETOT * 4);
  float* dinv_all = (float*)alloc((size_t)NTOT * 4);
  float* h_all    = (float*)alloc((size_t)HTOT * 4);
  float* xh_all   = (float*)alloc((size_t)HTOT * 4);
  float* eat      = (float*)alloc((size_t)ETOT * 64 * 4);   // ~176 MB
  (void)ws_size; (void)in_sizes; (void)n_in; (void)out_size;

  float* outp = (float*)d_out;

  k_zero<<<NBZ, 256, 0, stream>>>(outp);
  k_ea_all<<<NB_T2 + NB_H2 + NB_F2, 256, 0, stream>>>(ez, tmask, hmask,
      dgW_t, dgb_t, dgW_h, dgb_h, dgW_f, dgb_f, eat, w2_all);
  k_h_all<<<(HTOT + 255) / 256, 256, 0, stream>>>(nodez, wx, hub_wx, top_wx,
      hidx, tidx, gW_t, gW_h, gW_f, h_all);
  k_deg_all<<<NTOT, 256, 0, stream>>>(w2_all, dinv_all);
  k_xh_all<<<NTOT, 256, 0, stream>>>(w2_all, dinv_all, h_all, gb_t, gb_h, gb_f, xh_all);
  k_tri_tiled<<<TT_T + TT_H + TT_F, 256, 0, stream>>>(xh_all, tri_all);
  k_out<<<NBT4 + NBH4 + NBF4, 256, 0, stream>>>(
      eat, tri_all, tmask, hmask, cW_t, cb_t, cW_h, cb_h, cW_f, cb_f, outp);
}

// Round 5
// 720.849 us; speedup vs baseline: 1.2245x; 1.0182x over previous
//
#include <hip/hip_runtime.h>
#include <stdint.h>

#define NFULL 1024
#define NHUB  512
#define NTOP  256
#define EFULL 523776
#define EHUB  130816
#define ETOP  32640
#define ETOT  (ETOP + EHUB + EFULL)   // 687232
#define NTOT  (NTOP + NHUB + NFULL)   // 1792
// h/xh row-buffer offsets (floats): top 256*128, hub 512*64, full 1024*64
#define HOFF_H 32768
#define HOFF_F 65536
#define HTOT   131072
#define SLOPE 0.01f

// fused kernel A: ea blocks first (fill CUs with VALU work), then h, then
// zero blocks backfill -> zero's HBM writes overlap ea's compute.
#define NB_T2 255    // 32640/128
#define NB_H2 1022   // 130816/128
#define NB_F2 4092   // 523776/128
#define NB_EA 5369   // NB_T2+NB_H2+NB_F2
#define NB_H  512    // HTOT/256
#define NB_Z  65472  // EFULL*32/256
#define NB_A  (NB_EA + NB_H + NB_Z)

// k_tri_tiled: 64x64 tiles over upper-tri tile grid
#define TT_T 10      // nt=4  -> 4+3+2+1
#define TT_H 36      // nt=8
#define TT_F 136     // nt=16

// k_out: 8 threads/edge (two float4 each)
#define NBT8 1020    // ETOP*8/256
#define NBH8 4088    // EHUB*8/256
#define NBF8 16368   // EFULL*8/256

__device__ __forceinline__ int trioff(int i, int n){ return (i * (2 * n - i - 1)) >> 1; }

// A = [ea: leaky(ez@W+b) -> eat, mean -> w2] + [h = concat(nodez,wx)@gW] +
//     [zero out[:,0:128)] , horizontally fused; branch is block-uniform.
__global__ __launch_bounds__(256, 4)
void k_fusedA(const float* __restrict__ ez,
              const int* __restrict__ tmask, const int* __restrict__ hmask,
              const float* __restrict__ Wt, const float* __restrict__ bt,
              const float* __restrict__ Wh, const float* __restrict__ bh,
              const float* __restrict__ Wf, const float* __restrict__ bf,
              const float* __restrict__ nodez,
              const float* __restrict__ wx, const float* __restrict__ hwx,
              const float* __restrict__ twx,
              const int* __restrict__ hidx, const int* __restrict__ tidx,
              const float* __restrict__ gWt, const float* __restrict__ gWh,
              const float* __restrict__ gWf,
              float* __restrict__ eat, float* __restrict__ w2_all,
              float* __restrict__ h_all, float* __restrict__ out)
{
  __shared__ float sW[4096];
  __shared__ float sB[64];
  int b = blockIdx.x, tid = threadIdx.x;

  if (b < NB_EA){
    // ---- ea path (r1/r4-proven 2-threads-per-edge config) ----
    int bloc, w2off; const int* mask; const float* W; const float* bb;
    if (b < NB_T2)               { bloc = b;                 w2off = 0;           mask = tmask;   W = Wt; bb = bt; }
    else if (b < NB_T2 + NB_H2)  { bloc = b - NB_T2;         w2off = ETOP;        mask = hmask;   W = Wh; bb = bh; }
    else                         { bloc = b - NB_T2 - NB_H2; w2off = ETOP + EHUB; mask = nullptr; W = Wf; bb = bf; }
    {
      const float4* Wv = (const float4*)W;
      float4* sWv = (float4*)sW;
      #pragma unroll
      for (int q = 0; q < 4; q++) sWv[q * 256 + tid] = Wv[q * 256 + tid];
      if (tid < 64) sB[tid] = bb[tid];
    }
    __syncthreads();
    int e_loc = bloc * 128 + (tid >> 1);
    int c0 = (tid & 1) * 32;
    int ef = mask ? mask[e_loc] : e_loc;
    const float4* row4 = (const float4*)(ez + (size_t)ef * 64);

    float acc[32];
    #pragma unroll
    for (int j = 0; j < 32; j++) acc[j] = sB[c0 + j];
    #pragma unroll
    for (int k0 = 0; k0 < 64; k0 += 4){
      float4 a4 = row4[k0 >> 2];
      float av[4]; av[0]=a4.x; av[1]=a4.y; av[2]=a4.z; av[3]=a4.w;
      #pragma unroll
      for (int q = 0; q < 4; q++){
        float a = av[q];
        const float* wr = sW + (k0 + q) * 64 + c0;
        #pragma unroll
        for (int j0 = 0; j0 < 32; j0 += 4){
          float4 w4 = *(const float4*)(wr + j0);
          acc[j0+0] += a * w4.x;
          acc[j0+1] += a * w4.y;
          acc[j0+2] += a * w4.z;
          acc[j0+3] += a * w4.w;
        }
      }
    }
    float s = 0.f;
    #pragma unroll
    for (int j = 0; j < 32; j++){
      float v = acc[j];
      v = v >= 0.f ? v : SLOPE * v;
      acc[j] = v; s += v;
    }
    s += __shfl_xor(s, 1);
    if ((tid & 1) == 0) w2_all[w2off + e_loc] = s * (1.0f / 64.0f);
    float* orow = eat + (size_t)(w2off + e_loc) * 64 + c0;
    #pragma unroll
    for (int j0 = 0; j0 < 32; j0 += 4){
      float4 o; o.x = acc[j0]; o.y = acc[j0+1]; o.z = acc[j0+2]; o.w = acc[j0+3];
      *(float4*)(orow + j0) = o;
    }
  } else if (b < NB_EA + NB_H){
    // ---- h path ----
    int t = (b - NB_EA) * 256 + tid;
    int i, c, gout, nrow; const float* gW; const float* wxp; const int* gidx; float* hp;
    if (t < HOFF_H)      { gout = 128; i = t / 128;  c = t & 127; gW = gWt; wxp = twx; gidx = tidx; hp = h_all; }
    else if (t < HOFF_F) { int u = t - HOFF_H; gout = 64; i = u / 64; c = u & 63; gW = gWh; wxp = hwx; gidx = hidx; hp = h_all + HOFF_H; }
    else                 { int u = t - HOFF_F; gout = 64; i = u / 64; c = u & 63; gW = gWf; wxp = wx;  gidx = nullptr; hp = h_all + HOFF_F; }
    nrow = gidx ? gidx[i] : i;
    const float* nr = nodez + (size_t)nrow * 128;
    float acc = 0.f;
    for (int k = 0; k < 128; k++) acc += nr[k] * gW[k * gout + c];
    const float* wr = wxp + (size_t)i * 16;
    for (int k = 0; k < 16; k++) acc += wr[k] * gW[(128 + k) * gout + c];
    hp[(size_t)i * gout + c] = acc;
  } else {
    // ---- zero path: out[:, 0:128) ----
    int t = (b - NB_EA - NB_H) * 256 + tid;
    int row = t >> 5, c4 = t & 31;
    float4 z; z.x = 0.f; z.y = 0.f; z.z = 0.f; z.w = 0.f;
    *(float4*)(out + (size_t)row * 192 + c4 * 4) = z;
  }
}

// deg[i] = 1 + sum_j!=i w2[e(i,j)]; dinv = rsqrt(deg). 256 threads/block.
__global__ void k_deg_all(const float* __restrict__ w2_all, float* __restrict__ dinv_all)
{
  __shared__ float red[4];
  int b = blockIdx.x, l = threadIdx.x;
  int n, i, boff; const float* w2;
  if (b < NTOP)             { n = NTOP;  i = b;               boff = 0;           w2 = w2_all; }
  else if (b < NTOP + NHUB) { n = NHUB;  i = b - NTOP;        boff = NTOP;        w2 = w2_all + ETOP; }
  else                      { n = NFULL; i = b - NTOP - NHUB; boff = NTOP + NHUB; w2 = w2_all + ETOP + EHUB; }
  float s = 0.f;
  for (int j = l; j < n; j += 256){
    if (j == i) continue;
    int e = (j < i) ? (trioff(j, n) + i - j - 1) : (trioff(i, n) + j - i - 1);
    s += w2[e];
  }
  #pragma unroll
  for (int o = 32; o > 0; o >>= 1) s += __shfl_down(s, o);
  if ((l & 63) == 0) red[l >> 6] = s;
  __syncthreads();
  if (l == 0){
    float deg = red[0] + red[1] + red[2] + red[3] + 1.0f;
    dinv_all[boff + i] = (deg > 0.f) ? rsqrtf(deg) : 0.f;
  }
}

// xh[i][c] = leaky( dinv[i] * sum_j coef(i,j)*dinv[j]*h[j][c] + b[c] )
// Coefs staged in LDS; hot loop = broadcast-coef x float4 h-stream.
__global__ void k_xh_all(const float* __restrict__ w2_all, const float* __restrict__ dinv_all,
                         const float* __restrict__ h_all,
                         const float* __restrict__ gbt, const float* __restrict__ gbh,
                         const float* __restrict__ gbf,
                         float* __restrict__ xh_all)
{
  __shared__ float coef[1024];
  __shared__ float4 part4[256];
  int b = blockIdx.x, tid = threadIdx.x;
  int n, i, gout; const float* w2; const float* dinv; const float* hb; const float* gb; float* xb;
  if (b < NTOP){
    n = NTOP; i = b; gout = 128;
    w2 = w2_all; dinv = dinv_all; hb = h_all; gb = gbt; xb = xh_all;
  } else if (b < NTOP + NHUB){
    n = NHUB; i = b - NTOP; gout = 64;
    w2 = w2_all + ETOP; dinv = dinv_all + NTOP; hb = h_all + HOFF_H; gb = gbh; xb = xh_all + HOFF_H;
  } else {
    n = NFULL; i = b - NTOP - NHUB; gout = 64;
    w2 = w2_all + ETOP + EHUB; dinv = dinv_all + NTOP + NHUB; hb = h_all + HOFF_F; gb = gbf; xb = xh_all + HOFF_F;
  }
  for (int j = tid; j < n; j += 256){
    float w;
    if (j == i) w = 1.0f;
    else {
      int e = (j < i) ? (trioff(j, n) + i - j - 1) : (trioff(i, n) + j - i - 1);
      w = w2[e];
    }
    coef[j] = w * dinv[j];
  }
  __syncthreads();
  int g4 = gout >> 2;           // 32 (top) or 16
  int SJ = 256 / g4;            // 8 or 16
  int c4 = tid & (g4 - 1);
  int js = tid / g4;
  const float4* h4 = (const float4*)hb;
  float4 acc; acc.x = acc.y = acc.z = acc.w = 0.f;
  #pragma unroll 4
  for (int j = js; j < n; j += SJ){
    float cf = coef[j];
    float4 hv = h4[(size_t)j * g4 + c4];
    acc.x += cf * hv.x; acc.y += cf * hv.y;
    acc.z += cf * hv.z; acc.w += cf * hv.w;
  }
  part4[tid] = acc;
  __syncthreads();
  if (js == 0){
    float4 s = acc;
    for (int q = 1; q < SJ; q++){
      float4 p = part4[q * g4 + c4];
      s.x += p.x; s.y += p.y; s.z += p.z; s.w += p.w;
    }
    float di = dinv[i];
    int c = c4 * 4;
    float4 o;
    o.x = di * s.x + gb[c+0]; o.y = di * s.y + gb[c+1];
    o.z = di * s.z + gb[c+2]; o.w = di * s.w + gb[c+3];
    o.x = o.x >= 0.f ? o.x : SLOPE * o.x;
    o.y = o.y >= 0.f ? o.y : SLOPE * o.y;
    o.z = o.z >= 0.f ? o.z : SLOPE * o.z;
    o.w = o.w >= 0.f ? o.w : SLOPE * o.w;
    *(float4*)(xb + (size_t)i * gout + c) = o;
  }
}

// tri = sigmoid(xh @ xh^T) on strict upper triangle, tiled LDS GEMM.
__global__ __launch_bounds__(256)
void k_tri_tiled(const float* __restrict__ xh_all, float* __restrict__ tri_all)
{
  __shared__ float sXi[8192];   // up to 64 x 128
  __shared__ float sXj[8192];
  int b = blockIdx.x, tid = threadIdx.x;
  int n, g, nt, tt, csh; const float* xb; float* tb;
  if (b < TT_T)        { n = NTOP;  g = 128; nt = 4;  csh = 5; tt = b;            xb = xh_all;          tb = tri_all; }
  else if (b < TT_T+TT_H){ n = NHUB; g = 64; nt = 8;  csh = 4; tt = b - TT_T;     xb = xh_all + HOFF_H; tb = tri_all + ETOP; }
  else                 { n = NFULL; g = 64;  nt = 16; csh = 4; tt = b - TT_T - TT_H; xb = xh_all + HOFF_F; tb = tri_all + ETOP + EHUB; }
  int bi = 0, t = tt;
  while (t >= nt - bi){ t -= nt - bi; bi++; }
  int bj = bi + t;
  int cpr = g >> 2;
  int nch = 64 * cpr;
  const float* gi = xb + (size_t)(bi * 64) * g;
  const float* gj = xb + (size_t)(bj * 64) * g;
  for (int idx = tid; idx < nch; idx += 256){
    int row = idx >> csh;
    int c = idx & (cpr - 1);
    int sw = (c ^ ((row >> 2) & 7)) << 2;
    float4 v = *(const float4*)(gi + (size_t)row * g + c * 4);
    *(float4*)(sXi + row * g + sw) = v;
    float4 w = *(const float4*)(gj + (size_t)row * g + c * 4);
    *(float4*)(sXj + row * g + sw) = w;
  }
  __syncthreads();
  int ii = tid >> 4, jj = tid & 15;
  float acc[4][4];
  #pragma unroll
  for (int a = 0; a < 4; a++)
    #pragma unroll
    for (int q = 0; q < 4; q++) acc[a][q] = 0.f;
  for (int ck = 0; ck < cpr; ck++){
    int swi = (ck ^ (ii & 7)) << 2;
    int swj = (ck ^ (jj & 7)) << 2;
    float4 xi[4], xj[4];
    #pragma unroll
    for (int a = 0; a < 4; a++) xi[a] = *(const float4*)(sXi + (ii * 4 + a) * g + swi);
    #pragma unroll
    for (int q = 0; q < 4; q++) xj[q] = *(const float4*)(sXj + (jj * 4 + q) * g + swj);
    #pragma unroll
    for (int a = 0; a < 4; a++)
      #pragma unroll
      for (int q = 0; q < 4; q++){
        acc[a][q] += xi[a].x * xj[q].x;
        acc[a][q] += xi[a].y * xj[q].y;
        acc[a][q] += xi[a].z * xj[q].z;
        acc[a][q] += xi[a].w * xj[q].w;
      }
  }
  #pragma unroll
  for (int a = 0; a < 4; a++){
    int I = bi * 64 + ii * 4 + a;
    int base = trioff(I, n) - I - 1;
    #pragma unroll
    for (int q = 0; q < 4; q++){
      int J = bj * 64 + jj * 4 + q;
      if (I < J){
        float s = acc[a][q];
        tb[base + J] = 1.f / (1.f + __expf(-s));
      }
    }
  }
}

// Value writer keyed by BRANCH edge; 8 threads/edge, two float4 per thread.
__global__ __launch_bounds__(256)
void k_out(const float* __restrict__ eat, const float* __restrict__ tri_all,
           const int* __restrict__ tmask, const int* __restrict__ hmask,
           const float* __restrict__ cwT, const float* __restrict__ cbT,
           const float* __restrict__ cwH, const float* __restrict__ cbH,
           const float* __restrict__ cwF, const float* __restrict__ cbF,
           float* __restrict__ out)
{
  __shared__ float scw[64], scb[64];
  int b = blockIdx.x, tid = threadIdx.x;
  int boff, col, u; const int* mask; const float* cwp; const float* cbp;
  if (b < NBT8)             { u = b * 256 + tid;                 boff = 0;           col = 0;   mask = tmask;   cwp = cwT; cbp = cbT; }
  else if (b < NBT8 + NBH8) { u = (b - NBT8) * 256 + tid;        boff = ETOP;        col = 64;  mask = hmask;   cwp = cwH; cbp = cbH; }
  else                      { u = (b - NBT8 - NBH8) * 256 + tid; boff = ETOP + EHUB; col = 128; mask = nullptr; cwp = cwF; cbp = cbF; }
  if (tid < 64){ scw[tid] = cwp[tid]; scb[tid] = cbp[tid]; }
  __syncthreads();
  int eb = u >> 3, c8 = u & 7;
  int erow = mask ? mask[eb] : eb;
  float tv = tri_all[boff + eb];
  const float4* q = (const float4*)(eat + (size_t)(boff + eb) * 64 + c8 * 8);
  float4 v0 = q[0], v1 = q[1];
  int h0 = c8 * 8;
  float4 o0, o1;
  o0.x = v0.x * (1.f + tv * scw[h0+0] + scb[h0+0]);
  o0.y = v0.y * (1.f + tv * scw[h0+1] + scb[h0+1]);
  o0.z = v0.z * (1.f + tv * scw[h0+2] + scb[h0+2]);
  o0.w = v0.w * (1.f + tv * scw[h0+3] + scb[h0+3]);
  o1.x = v1.x * (1.f + tv * scw[h0+4] + scb[h0+4]);
  o1.y = v1.y * (1.f + tv * scw[h0+5] + scb[h0+5]);
  o1.z = v1.z * (1.f + tv * scw[h0+6] + scb[h0+6]);
  o1.w = v1.w * (1.f + tv * scw[h0+7] + scb[h0+7]);
  float* p = out + (size_t)erow * 192 + col + h0;
  *(float4*)p = o0;
  *(float4*)(p + 4) = o1;
}

extern "C" void kernel_launch(void* const* d_in, const int* in_sizes, int n_in,
                              void* d_out, int out_size, void* d_ws, size_t ws_size,
                              hipStream_t stream)
{
  const float* nodez  = (const float*)d_in[0];
  const float* wx     = (const float*)d_in[1];
  const float* hub_wx = (const float*)d_in[2];
  const float* top_wx = (const float*)d_in[3];
  const float* ez     = (const float*)d_in[4];
  const int* hidx  = (const int*)d_in[8];
  const int* tidx  = (const int*)d_in[9];
  const int* hmask = (const int*)d_in[13];
  const int* tmask = (const int*)d_in[14];
  const float* dgW_t = (const float*)d_in[15];
  const float* dgb_t = (const float*)d_in[16];
  const float* gW_t  = (const float*)d_in[17];
  const float* gb_t  = (const float*)d_in[18];
  const float* cW_t  = (const float*)d_in[19];
  const float* cb_t  = (const float*)d_in[20];
  const float* dgW_h = (const float*)d_in[21];
  const float* dgb_h = (const float*)d_in[22];
  const float* gW_h  = (const float*)d_in[23];
  const float* gb_h  = (const float*)d_in[24];
  const float* cW_h  = (const float*)d_in[25];
  const float* cb_h  = (const float*)d_in[26];
  const float* dgW_f = (const float*)d_in[27];
  const float* dgb_f = (const float*)d_in[28];
  const float* gW_f  = (const float*)d_in[29];
  const float* gb_f  = (const float*)d_in[30];
  const float* cW_f  = (const float*)d_in[31];
  const float* cb_f  = (const float*)d_in[32];

  char* w = (char*)d_ws;
  size_t off = 0;
  auto alloc = [&](size_t bytes) -> char* {
    char* p = w + off;
    off += (bytes + 255) & ~(size_t)255;
    return p;
  };
  float* w2_all   = (float*)alloc((size_t)ETOT * 4);
  float* tri_all  = (float*)alloc((size_t)ETOT * 4);
  float* dinv_all = (float*)alloc((size_t)NTOT * 4);
  float* h_all    = (float*)alloc((size_t)HTOT * 4);
  float* xh_all   = (float*)alloc((size_t)HTOT * 4);
  float* eat      = (float*)alloc((size_t)ETOT * 64 * 4);   // ~176 MB
  (void)ws_size; (void)in_sizes; (void)n_in; (void)out_size;

  float* outp = (float*)d_out;

  k_fusedA<<<NB_A, 256, 0, stream>>>(ez, tmask, hmask,
      dgW_t, dgb_t, dgW_h, dgb_h, dgW_f, dgb_f,
      nodez, wx, hub_wx, top_wx, hidx, tidx, gW_t, gW_h, gW_f,
      eat, w2_all, h_all, outp);
  k_deg_all<<<NTOT, 256, 0, stream>>>(w2_all, dinv_all);
  k_xh_all<<<NTOT, 256, 0, stream>>>(w2_all, dinv_all, h_all, gb_t, gb_h, gb_f, xh_all);
  k_tri_tiled<<<TT_T + TT_H + TT_F, 256, 0, stream>>>(xh_all, tri_all);
  k_out<<<NBT8 + NBH8 + NBF8, 256, 0, stream>>>(
      eat, tri_all, tmask, hmask, cW_t, cb_t, cW_h, cb_h, cW_f, cb_f, outp);
}